// Round 19
// baseline (199.043 us; speedup 1.0000x reference)
//
#include <hip/hip_runtime.h>
#include <hip/hip_fp16.h>
#include <math.h>

#define NEG 0.2f

typedef __attribute__((ext_vector_type(8))) short bf16x8;
typedef __attribute__((ext_vector_type(4))) float f32x4;

__device__ __forceinline__ float lrelu(float x){ return x > 0.f ? x : NEG*x; }

__device__ __forceinline__ float bflo(unsigned u){ return __uint_as_float(u << 16); }
__device__ __forceinline__ float bfhi(unsigned u){ return __uint_as_float(u & 0xffff0000u); }

// select a0..a3 by 2-bit index encoded as booleans (bit0, bit1)
__device__ __forceinline__ float selh(float a0, float a1, float a2, float a3,
                                      bool bit0, bool bit1){
  float lo = bit0 ? a1 : a0;
  float hi = bit0 ? a3 : a2;
  return bit1 ? hi : lo;
}

__device__ __forceinline__ unsigned short f2bf(float x){
  unsigned u = __float_as_uint(x);
  u += 0x7fffu + ((u >> 16) & 1u);     // RNE
  return (unsigned short)(u >> 16);
}

#define FMA8(e, h) \
  acc[0]=fmaf(e,bflo(h.x),acc[0]); acc[1]=fmaf(e,bfhi(h.x),acc[1]); \
  acc[2]=fmaf(e,bflo(h.y),acc[2]); acc[3]=fmaf(e,bfhi(h.y),acc[3]); \
  acc[4]=fmaf(e,bflo(h.z),acc[4]); acc[5]=fmaf(e,bfhi(h.z),acc[5]); \
  acc[6]=fmaf(e,bflo(h.w),acc[6]); acc[7]=fmaf(e,bfhi(h.w),acc[7]);

__device__ __forceinline__ int wt_addr(int col, int k){   // address in shorts, K=128
  int g = (k >> 3) ^ (col & 7);
  return col*128 + g*8 + (k & 7);
}

// ---- MERGED: fill (blocks [0,FB)) + gemm1 (blocks [FB, FB+gb)) ----
// fill: bucket-CSR, inlined int64/int32 detection. gemm1: MFMA + fused alpha1.
// The two are data-independent; heterogeneous blocks overlap atomic-latency
// work with MFMA work on the same dispatch.
__global__ __launch_bounds__(256) void fill_gemm1_kernel(
    const int* __restrict__ ei, int* __restrict__ cnt, int* __restrict__ adj, int E,
    const float* __restrict__ x, const float* __restrict__ W,
    const float* __restrict__ asrcw, const float* __restrict__ adstw,
    unsigned short* __restrict__ h1b, float* __restrict__ as1, float* __restrict__ ad1,
    int N, int FB){
  __shared__ unsigned short wt[256*128];   // 65536 B (gemm1 path)
  __shared__ int s_is64;                   // (fill path)

  if ((int)blockIdx.x < FB){
    // ---------------- fill path ----------------
    if (threadIdx.x < 64){
      int v = ei[2*threadIdx.x + 1];
      unsigned long long b = __ballot(v != 0);
      if (threadIdx.x == 0) s_is64 = (b == 0ULL) ? 1 : 0;   // 1 => int64 layout
    }
    __syncthreads();
    int is64 = s_is64;
    int stride = FB * 256;
    for (int i = blockIdx.x*256 + threadIdx.x; i < E; i += stride){
      int s = is64 ? ei[2*i]       : ei[i];
      int d = is64 ? ei[2*(E + i)] : ei[E + i];
      int pos = atomicAdd(&cnt[d], 1);
      if (pos < 64) adj[(d << 6) + pos] = s;   // P(deg>64) ~ 1e-13
    }
    return;
  }

  // ---------------- gemm1 path ----------------
  int t = threadIdx.x;
  int lane = t & 63, w = t >> 6;
  int row0 = ((int)blockIdx.x - FB) * 64 + w * 16;

  // A-frags from x: row = lane&15, k = (lane>>4)*8 + j
  int arow = row0 + (lane & 15);
  if (arow >= N) arow = N - 1;
  const float* xr = x + (size_t)arow * 128 + (lane >> 4) * 8;
  bf16x8 afrag[4];
  #pragma unroll
  for (int kk = 0; kk < 4; kk++){
    float4 p0 = *reinterpret_cast<const float4*>(xr + kk*32);
    float4 p1 = *reinterpret_cast<const float4*>(xr + kk*32 + 4);
    afrag[kk][0] = (short)f2bf(p0.x); afrag[kk][1] = (short)f2bf(p0.y);
    afrag[kk][2] = (short)f2bf(p0.z); afrag[kk][3] = (short)f2bf(p0.w);
    afrag[kk][4] = (short)f2bf(p1.x); afrag[kk][5] = (short)f2bf(p1.y);
    afrag[kk][6] = (short)f2bf(p1.z); afrag[kk][7] = (short)f2bf(p1.w);
  }

  // stage W1 transposed: thread t owns col c=t; coalesced global reads
  int c = t;
  for (int k0 = 0; k0 < 128; k0 += 8){
    bf16x8 v;
    #pragma unroll
    for (int j = 0; j < 8; j++) v[j] = (short)f2bf(W[(size_t)(k0+j)*256 + c]);
    *reinterpret_cast<bf16x8*>(&wt[wt_addr(c, k0)]) = v;
  }
  __syncthreads();

  f32x4 acc[16];
  #pragma unroll
  for (int n = 0; n < 16; n++) acc[n] = (f32x4){0.f,0.f,0.f,0.f};
  #pragma unroll
  for (int kk = 0; kk < 4; kk++){
    #pragma unroll
    for (int n = 0; n < 16; n++){
      bf16x8 b = *reinterpret_cast<const bf16x8*>(
          &wt[wt_addr(n*16 + (lane & 15), kk*32 + (lane >> 4)*8)]);
      acc[n] = __builtin_amdgcn_mfma_f32_16x16x32_bf16(afrag[kk], b, acc[n], 0, 0, 0);
    }
  }

  // store h1b: row = row0 + (lane>>4)*4 + r, col = n*16 + (lane&15)
  int rbase = row0 + (lane >> 4)*4;
  int cbase = lane & 15;
  #pragma unroll
  for (int n = 0; n < 16; n++){
    #pragma unroll
    for (int r = 0; r < 4; r++){
      int row = rbase + r;
      if (row < N) h1b[(size_t)row*256 + n*16 + cbase] = f2bf(acc[n][r]);
    }
  }

  // fused alpha1
  float av[16], dv[16];
  #pragma unroll
  for (int n = 0; n < 16; n++){
    av[n] = asrcw[n*16 + cbase];
    dv[n] = adstw[n*16 + cbase];
  }
  #pragma unroll
  for (int r = 0; r < 4; r++){
    int row = rbase + r;
    float hs[4], hd[4];
    #pragma unroll
    for (int h = 0; h < 4; h++){
      float ps = 0.f, pd = 0.f;
      #pragma unroll
      for (int q = 0; q < 4; q++){
        int n = h*4 + q;
        ps = fmaf(acc[n][r], av[n], ps);
        pd = fmaf(acc[n][r], dv[n], pd);
      }
      #pragma unroll
      for (int off = 1; off < 16; off <<= 1){
        ps += __shfl_xor(ps, off, 64);
        pd += __shfl_xor(pd, off, 64);
      }
      hs[h] = ps; hd[h] = pd;
    }
    if (cbase == 0 && row < N){
      *reinterpret_cast<float4*>(as1 + (size_t)row*4) = make_float4(hs[0],hs[1],hs[2],hs[3]);
      *reinterpret_cast<float4*>(ad1 + (size_t)row*4) = make_float4(hd[0],hd[1],hd[2],hd[3]);
    }
  }
}

// ---- edge_exp (layer 1): wave per node; per-edge softmax weights (fp16) +
//      per-node denominator & self-exp (fp32). ----
__global__ void edge_exp_kernel(const float* __restrict__ as1, const float* __restrict__ ad1,
                                const int* __restrict__ cnt, const int* __restrict__ adj,
                                __half* __restrict__ exarr, float* __restrict__ den, int N){
  int node = (blockIdx.x*blockDim.x + threadIdx.x) >> 6;
  int lane = threadIdx.x & 63;
  if (node >= N) return;
  int cn = cnt[node]; if (cn > 64) cn = 64;
  int beg = node << 6;
  bool val = lane < cn;
  int src = val ? adj[beg + lane] : 0;
  float4 dv = *reinterpret_cast<const float4*>(ad1 + (size_t)node*4);
  float4 sv = *reinterpret_cast<const float4*>(as1 + (size_t)src*4);
  float ex0 = val ? __expf(lrelu(sv.x + dv.x)) : 0.f;
  float ex1 = val ? __expf(lrelu(sv.y + dv.y)) : 0.f;
  float ex2 = val ? __expf(lrelu(sv.z + dv.z)) : 0.f;
  float ex3 = val ? __expf(lrelu(sv.w + dv.w)) : 0.f;

  if (val){
    __half2 p0 = __floats2half2_rn(ex0, ex1);
    __half2 p1 = __floats2half2_rn(ex2, ex3);
    uint2 o;
    o.x = *reinterpret_cast<unsigned*>(&p0);
    o.y = *reinterpret_cast<unsigned*>(&p1);
    *reinterpret_cast<uint2*>(exarr + (size_t)(beg + lane)*4) = o;
  }

  float sp0 = ex0, sp1 = ex1, sp2 = ex2, sp3 = ex3;
  #pragma unroll
  for (int off = 32; off; off >>= 1){
    sp0 += __shfl_xor(sp0, off, 64);
    sp1 += __shfl_xor(sp1, off, 64);
    sp2 += __shfl_xor(sp2, off, 64);
    sp3 += __shfl_xor(sp3, off, 64);
  }
  // self-loop
  float4 s2 = *reinterpret_cast<const float4*>(as1 + (size_t)node*4);
  float exs0 = __expf(lrelu(s2.x + dv.x));
  float exs1 = __expf(lrelu(s2.y + dv.y));
  float exs2 = __expf(lrelu(s2.z + dv.z));
  float exs3 = __expf(lrelu(s2.w + dv.w));
  if (lane == 0){
    *reinterpret_cast<float4*>(den + (size_t)node*8) =
        make_float4(sp0 + exs0, sp1 + exs1, sp2 + exs2, sp3 + exs3);
    *reinterpret_cast<float4*>(den + (size_t)node*8 + 4) =
        make_float4(exs0, exs1, exs2, exs3);
  }
}

// ---- layer-1 aggregation: TWO nodes per wave (half-wave per node, 32 lanes x
//      8 ch = 256). Independent gather streams per half -> 8 rows in flight.
//      32-bit addressing throughout. (Proven R18 structure.) ----
__global__ void agg1_kernel(const unsigned short* __restrict__ h1b,
                            const float* __restrict__ b1,
                            const int* __restrict__ cnt, const int* __restrict__ adj,
                            const __half* __restrict__ exarr, const float* __restrict__ den,
                            unsigned short* __restrict__ hact_b, int N){
  int wid  = (blockIdx.x*blockDim.x + threadIdx.x) >> 6;
  int lane = threadIdx.x & 63;
  int hf   = lane >> 5;                 // which node of the pair
  int node = (wid << 1) + hf;
  if (node >= N) return;
  int sl = lane & 31;                   // channel slice: shorts sl*8 .. sl*8+7
  int hh = sl >> 3;                     // head of this lane's channels
  bool hb0 = (sl & 8) != 0, hb1 = (sl & 16) != 0;
  int cn = cnt[node]; if (cn > 64) cn = 64;
  unsigned beg = (unsigned)node << 6;
  const int* aj = adj + beg;
  const __half* exw = exarr + ((size_t)beg * 4);
  unsigned co = (unsigned)sl * 8;

  float acc[8];
  #pragma unroll
  for (int q = 0; q < 8; q++) acc[q] = 0.f;

  int j = 0;
  for (; j + 4 <= cn; j += 4){
    int s0 = aj[j], s1 = aj[j+1], s2 = aj[j+2], s3 = aj[j+3];
    float w0 = __half2float(exw[(unsigned)(j+0)*4 + hh]);
    float w1 = __half2float(exw[(unsigned)(j+1)*4 + hh]);
    float w2 = __half2float(exw[(unsigned)(j+2)*4 + hh]);
    float w3 = __half2float(exw[(unsigned)(j+3)*4 + hh]);
    uint4 h0 = *reinterpret_cast<const uint4*>(h1b + (((unsigned)s0 << 8) + co));
    uint4 h1 = *reinterpret_cast<const uint4*>(h1b + (((unsigned)s1 << 8) + co));
    uint4 h2 = *reinterpret_cast<const uint4*>(h1b + (((unsigned)s2 << 8) + co));
    uint4 h3 = *reinterpret_cast<const uint4*>(h1b + (((unsigned)s3 << 8) + co));
    FMA8(w0, h0); FMA8(w1, h1); FMA8(w2, h2); FMA8(w3, h3);
  }
  for (; j < cn; j++){
    int s0 = aj[j];
    float w0 = __half2float(exw[(unsigned)j*4 + hh]);
    uint4 h0 = *reinterpret_cast<const uint4*>(h1b + (((unsigned)s0 << 8) + co));
    FMA8(w0, h0);
  }

  // epilogue — fully per-half (this half owns all 256 channels of its node)
  float4 dn  = *reinterpret_cast<const float4*>(den + (size_t)node*8);
  float4 dsf = *reinterpret_cast<const float4*>(den + (size_t)node*8 + 4);
  float dh  = selh(dn.x, dn.y, dn.z, dn.w, hb0, hb1);
  float ehs = selh(dsf.x, dsf.y, dsf.z, dsf.w, hb0, hb1);
  uint4 hv = *reinterpret_cast<const uint4*>(h1b + (((unsigned)node << 8) + co));
  FMA8(ehs, hv);

  float rinv = 1.0f / (dh + 1e-16f);
  float4 bA = *reinterpret_cast<const float4*>(b1 + co);
  float4 bB = *reinterpret_cast<const float4*>(b1 + co + 4);
  float o[8];
  o[0] = acc[0]*rinv + bA.x; o[1] = acc[1]*rinv + bA.y;
  o[2] = acc[2]*rinv + bA.z; o[3] = acc[3]*rinv + bA.w;
  o[4] = acc[4]*rinv + bB.x; o[5] = acc[5]*rinv + bB.y;
  o[6] = acc[6]*rinv + bB.z; o[7] = acc[7]*rinv + bB.w;
  #pragma unroll
  for (int q = 0; q < 8; q++) o[q] = o[q] > 0.f ? o[q] : (__expf(o[q]) - 1.f);
  uint4 ob;
  ob.x = (unsigned)f2bf(o[0]) | ((unsigned)f2bf(o[1]) << 16);
  ob.y = (unsigned)f2bf(o[2]) | ((unsigned)f2bf(o[3]) << 16);
  ob.z = (unsigned)f2bf(o[4]) | ((unsigned)f2bf(o[5]) << 16);
  ob.w = (unsigned)f2bf(o[6]) | ((unsigned)f2bf(o[7]) << 16);
  *reinterpret_cast<uint4*>(hact_b + (((unsigned)node << 8) + co)) = ob;
}

// ---- GEMM2 via MFMA: h2 = hact_b @ W2  [N,256]x[256,16], fused alpha2 ----
__device__ __forceinline__ int wt2_addr(int col, int k){  // shorts, K=256
  int g = (k >> 3) ^ (col & 7);
  return col*256 + g*8 + (k & 7);
}

__global__ __launch_bounds__(256) void gemm2_mfma(const unsigned short* __restrict__ hact_b,
                             const float* __restrict__ W2,
                             const float* __restrict__ asrc2, const float* __restrict__ adst2,
                             float* __restrict__ h2, float* __restrict__ as2,
                             float* __restrict__ ad2, int N){
  __shared__ unsigned short wt[16*256];    // 8192 B
  int t = threadIdx.x;
  int lane = t & 63, w = t >> 6;
  int row0 = blockIdx.x * 64 + w * 16;

  // stage W2^T bf16: thread t owns k=t (row of W2), writes 16 cols
  {
    float4 r0 = *reinterpret_cast<const float4*>(W2 + (size_t)t*16);
    float4 r1 = *reinterpret_cast<const float4*>(W2 + (size_t)t*16 + 4);
    float4 r2 = *reinterpret_cast<const float4*>(W2 + (size_t)t*16 + 8);
    float4 r3 = *reinterpret_cast<const float4*>(W2 + (size_t)t*16 + 12);
    float wr[16] = {r0.x,r0.y,r0.z,r0.w, r1.x,r1.y,r1.z,r1.w,
                    r2.x,r2.y,r2.z,r2.w, r3.x,r3.y,r3.z,r3.w};
    #pragma unroll
    for (int cc = 0; cc < 16; cc++) wt[wt2_addr(cc, t)] = f2bf(wr[cc]);
  }

  // A-frag source row
  int arow = row0 + (lane & 15);
  if (arow >= N) arow = N - 1;
  const unsigned short* hr = hact_b + (size_t)arow*256 + (lane >> 4)*8;
  __syncthreads();

  f32x4 acc = (f32x4){0.f,0.f,0.f,0.f};
  #pragma unroll
  for (int kk = 0; kk < 8; kk++){
    bf16x8 a = *reinterpret_cast<const bf16x8*>(hr + kk*32);
    bf16x8 b = *reinterpret_cast<const bf16x8*>(
        &wt[wt2_addr(lane & 15, kk*32 + (lane >> 4)*8)]);
    acc = __builtin_amdgcn_mfma_f32_16x16x32_bf16(a, b, acc, 0, 0, 0);
  }

  // store h2 + fused alpha2 (cols = lane&15, rows = row0 + (lane>>4)*4 + r)
  int rbase = row0 + (lane >> 4)*4;
  int cbase = lane & 15;
  float avc = asrc2[cbase], dvc = adst2[cbase];
  #pragma unroll
  for (int r = 0; r < 4; r++){
    int row = rbase + r;
    if (row < N) h2[(size_t)row*16 + cbase] = acc[r];
    float ps = acc[r]*avc, pd = acc[r]*dvc;
    #pragma unroll
    for (int off = 1; off < 16; off <<= 1){
      ps += __shfl_xor(ps, off, 64);
      pd += __shfl_xor(pd, off, 64);
    }
    if (cbase == 0 && row < N){ as2[row] = ps; ad2[row] = pd; }
  }
}

// ---- layer-2 aggregation: single-chunk (cn<=64), shfl-decoupled. ----
__global__ void agg2_kernel(const float* __restrict__ h2, const float* __restrict__ as2,
                            const float* __restrict__ ad2, const float* __restrict__ b2,
                            const int* __restrict__ cnt, const int* __restrict__ adj,
                            float* __restrict__ out, int N){
  int node = (blockIdx.x*blockDim.x + threadIdx.x) >> 6;
  int lane = threadIdx.x & 63;
  if (node >= N) return;
  int cn = cnt[node]; if (cn > 64) cn = 64;
  int beg = node << 6;
  int g = lane >> 4, c = lane & 15;

  bool val = lane < cn;
  int srcl = val ? adj[beg + lane] : 0;   // invalid slots -> node 0 (safe address)
  float adn = ad2[node];

  // prefetch this group's h2 rows via shfl of srcl — independent of the exp chain
  float v[16];
  #pragma unroll
  for (int q = 0; q < 16; q++){
    v[q] = 0.f;
    if (4*q < cn){                        // uniform branch (cn wave-uniform)
      int sj = __shfl(srcl, 4*q + g, 64); // 0 for invalid slots
      v[q] = h2[((unsigned)sj*16u + (unsigned)c)];
    }
  }

  // exp chain: random 4B as2 gather, overlapped with the row loads above
  float e = val ? lrelu(as2[srcl] + adn) : -3e38f;
  float ex = __expf(e);                   // invalid -> 0
  float sp = ex;
  #pragma unroll
  for (int off = 32; off; off >>= 1) sp += __shfl_xor(sp, off, 64);
  float eself = __expf(lrelu(as2[node] + adn));
  sp += eself;

  float acc = 0.f;
  #pragma unroll
  for (int q = 0; q < 16; q++){
    if (4*q < cn){
      float wj = __shfl(ex, 4*q + g, 64); // 0 for invalid slots -> FMA no-op
      acc = fmaf(wj, v[q], acc);
    }
  }
  // combine group partials: lanes {c, c+16, c+32, c+48} hold same channel
  acc += __shfl_xor(acc, 16, 64);
  acc += __shfl_xor(acc, 32, 64);

  if (g == 0){   // lanes 0..15 finalize
    acc = fmaf(eself, h2[(size_t)node*16 + c], acc);
    float vv = acc / (sp + 1e-16f) + b2[c];
    float mx = vv;
    #pragma unroll
    for (int off = 1; off < 16; off <<= 1) mx = fmaxf(mx, __shfl_xor(mx, off, 64));
    float se = __expf(vv - mx);
    #pragma unroll
    for (int off = 1; off < 16; off <<= 1) se += __shfl_xor(se, off, 64);
    out[(size_t)node*16 + c] = vv - mx - logf(se);
  }
}

extern "C" void kernel_launch(void* const* d_in, const int* in_sizes, int n_in,
                              void* d_out, int out_size, void* d_ws, size_t ws_size,
                              hipStream_t stream){
  const float* x    = (const float*)d_in[0];
  const int*   ei   = (const int*)d_in[1];
  const float* W1   = (const float*)d_in[2];
  const float* as1w = (const float*)d_in[3];
  const float* ad1w = (const float*)d_in[4];
  const float* b1   = (const float*)d_in[5];
  const float* W2   = (const float*)d_in[6];
  const float* as2w = (const float*)d_in[7];
  const float* ad2w = (const float*)d_in[8];
  const float* b2   = (const float*)d_in[9];
  float* out = (float*)d_out;

  int N = in_sizes[0] / 128;   // 50000
  int E = in_sizes[1] / 2;     // 800000

  char* p = (char*)d_ws;
  size_t off = 0;
  auto alloc = [&](size_t b){ size_t c = off; off = (off + b + 255) & ~(size_t)255; return c; };
  unsigned short* h1b   = (unsigned short*)(p + alloc((size_t)N*256*2)); // 25.6 MB bf16
  unsigned short* hact_b= (unsigned short*)(p + alloc((size_t)N*256*2)); // 25.6 MB bf16
  float* h2     = (float*)(p + alloc((size_t)N*16*4));    // 3.2 MB
  float* as1    = (float*)(p + alloc((size_t)N*4*4));
  float* ad1    = (float*)(p + alloc((size_t)N*4*4));
  float* as2    = (float*)(p + alloc((size_t)N*4));
  float* ad2    = (float*)(p + alloc((size_t)N*4));
  int*   cnt    = (int*)(p + alloc((size_t)N*4));
  int*   adj    = (int*)(p + alloc((size_t)N*64*4));      // 12.8 MB bucket CSR
  __half* exarr = (__half*)(p + alloc((size_t)N*64*4*2)); // 25.6 MB fp16 weights (layer 1)
  float* den    = (float*)(p + alloc((size_t)N*8*4));     // 1.6 MB denom + self-exp

  int FB = 1024;                 // fill blocks
  int gb = (N + 63) / 64;        // gemm1 blocks

  hipMemsetAsync(cnt, 0, (size_t)N*4, stream);
  fill_gemm1_kernel<<<FB + gb, 256, 0, stream>>>(ei, cnt, adj, E,
      x, W1, as1w, ad1w, h1b, as1, ad1, N, FB);
  edge_exp_kernel<<<(N*64 + 255)/256, 256, 0, stream>>>(as1, ad1, cnt, adj, exarr, den, N);
  agg1_kernel<<<(((N+1)/2)*64 + 255)/256, 256, 0, stream>>>(h1b, b1, cnt, adj, exarr, den, hact_b, N);
  gemm2_mfma<<<(N + 63)/64, 256, 0, stream>>>(hact_b, W2, as2w, ad2w, h2, as2, ad2, N);
  agg2_kernel<<<(N*64 + 255)/256, 256, 0, stream>>>(h2, as2, ad2, b2, cnt, adj, out, N);
}

// Round 20
// 176.521 us; speedup vs baseline: 1.1276x; 1.1276x over previous
//
#include <hip/hip_runtime.h>
#include <math.h>

#define NEG 0.2f

typedef __attribute__((ext_vector_type(8))) short bf16x8;
typedef __attribute__((ext_vector_type(4))) float f32x4;

__device__ __forceinline__ float lrelu(float x){ return x > 0.f ? x : NEG*x; }

__device__ __forceinline__ float bflo(unsigned u){ return __uint_as_float(u << 16); }
__device__ __forceinline__ float bfhi(unsigned u){ return __uint_as_float(u & 0xffff0000u); }

// select a0..a3 by 2-bit index encoded as booleans (bit0, bit1)
__device__ __forceinline__ float selh(float a0, float a1, float a2, float a3,
                                      bool bit0, bool bit1){
  float lo = bit0 ? a1 : a0;
  float hi = bit0 ? a3 : a2;
  return bit1 ? hi : lo;
}

__device__ __forceinline__ unsigned short f2bf(float x){
  unsigned u = __float_as_uint(x);
  u += 0x7fffu + ((u >> 16) & 1u);     // RNE
  return (unsigned short)(u >> 16);
}

#define FMA8(e, h) \
  acc[0]=fmaf(e,bflo(h.x),acc[0]); acc[1]=fmaf(e,bfhi(h.x),acc[1]); \
  acc[2]=fmaf(e,bflo(h.y),acc[2]); acc[3]=fmaf(e,bfhi(h.y),acc[3]); \
  acc[4]=fmaf(e,bflo(h.z),acc[4]); acc[5]=fmaf(e,bfhi(h.z),acc[5]); \
  acc[6]=fmaf(e,bflo(h.w),acc[6]); acc[7]=fmaf(e,bfhi(h.w),acc[7]);

// ---- single-pass bucket-CSR fill with inlined int64/int32 detection ----
__global__ void fill_kernel(const int* __restrict__ ei,
                            int* __restrict__ cnt, int* __restrict__ adj, int E){
  __shared__ int s_is64;
  if (threadIdx.x < 64){
    int v = ei[2*threadIdx.x + 1];
    unsigned long long b = __ballot(v != 0);
    if (threadIdx.x == 0) s_is64 = (b == 0ULL) ? 1 : 0;   // 1 => int64 layout
  }
  __syncthreads();
  int is64 = s_is64;
  int stride = gridDim.x * blockDim.x;
  for (int i = blockIdx.x*blockDim.x + threadIdx.x; i < E; i += stride){
    int s = is64 ? ei[2*i]       : ei[i];
    int d = is64 ? ei[2*(E + i)] : ei[E + i];
    int pos = atomicAdd(&cnt[d], 1);
    if (pos < 64) adj[(d << 6) + pos] = s;   // P(deg>64) ~ 1e-13 for this graph
  }
}

// ---- GEMM1 via MFMA: h1b = bf16(x @ W1)  [N,128]x[128,256], fused alpha1 ----
__device__ __forceinline__ int wt_addr(int col, int k){   // address in shorts, K=128
  int g = (k >> 3) ^ (col & 7);
  return col*128 + g*8 + (k & 7);
}

__global__ __launch_bounds__(256) void gemm1_mfma(const float* __restrict__ x,
                             const float* __restrict__ W,
                             const float* __restrict__ asrcw, const float* __restrict__ adstw,
                             unsigned short* __restrict__ h1b,
                             float* __restrict__ as1, float* __restrict__ ad1, int N){
  __shared__ unsigned short wt[256*128];   // 65536 B
  int t = threadIdx.x;
  int lane = t & 63, w = t >> 6;
  int row0 = blockIdx.x * 64 + w * 16;

  // A-frags from x: row = lane&15, k = (lane>>4)*8 + j
  int arow = row0 + (lane & 15);
  if (arow >= N) arow = N - 1;
  const float* xr = x + (size_t)arow * 128 + (lane >> 4) * 8;
  bf16x8 afrag[4];
  #pragma unroll
  for (int kk = 0; kk < 4; kk++){
    float4 p0 = *reinterpret_cast<const float4*>(xr + kk*32);
    float4 p1 = *reinterpret_cast<const float4*>(xr + kk*32 + 4);
    afrag[kk][0] = (short)f2bf(p0.x); afrag[kk][1] = (short)f2bf(p0.y);
    afrag[kk][2] = (short)f2bf(p0.z); afrag[kk][3] = (short)f2bf(p0.w);
    afrag[kk][4] = (short)f2bf(p1.x); afrag[kk][5] = (short)f2bf(p1.y);
    afrag[kk][6] = (short)f2bf(p1.z); afrag[kk][7] = (short)f2bf(p1.w);
  }

  // stage W1 transposed: thread t owns col c=t; coalesced global reads
  int c = t;
  for (int k0 = 0; k0 < 128; k0 += 8){
    bf16x8 v;
    #pragma unroll
    for (int j = 0; j < 8; j++) v[j] = (short)f2bf(W[(size_t)(k0+j)*256 + c]);
    *reinterpret_cast<bf16x8*>(&wt[wt_addr(c, k0)]) = v;
  }
  __syncthreads();

  f32x4 acc[16];
  #pragma unroll
  for (int n = 0; n < 16; n++) acc[n] = (f32x4){0.f,0.f,0.f,0.f};
  #pragma unroll
  for (int kk = 0; kk < 4; kk++){
    #pragma unroll
    for (int n = 0; n < 16; n++){
      bf16x8 b = *reinterpret_cast<const bf16x8*>(
          &wt[wt_addr(n*16 + (lane & 15), kk*32 + (lane >> 4)*8)]);
      acc[n] = __builtin_amdgcn_mfma_f32_16x16x32_bf16(afrag[kk], b, acc[n], 0, 0, 0);
    }
  }

  // store h1b: row = row0 + (lane>>4)*4 + r, col = n*16 + (lane&15)
  int rbase = row0 + (lane >> 4)*4;
  int cbase = lane & 15;
  #pragma unroll
  for (int n = 0; n < 16; n++){
    #pragma unroll
    for (int r = 0; r < 4; r++){
      int row = rbase + r;
      if (row < N) h1b[(size_t)row*256 + n*16 + cbase] = f2bf(acc[n][r]);
    }
  }

  // fused alpha1
  float av[16], dv[16];
  #pragma unroll
  for (int n = 0; n < 16; n++){
    av[n] = asrcw[n*16 + cbase];
    dv[n] = adstw[n*16 + cbase];
  }
  #pragma unroll
  for (int r = 0; r < 4; r++){
    int row = rbase + r;
    float hs[4], hd[4];
    #pragma unroll
    for (int h = 0; h < 4; h++){
      float ps = 0.f, pd = 0.f;
      #pragma unroll
      for (int q = 0; q < 4; q++){
        int n = h*4 + q;
        ps = fmaf(acc[n][r], av[n], ps);
        pd = fmaf(acc[n][r], dv[n], pd);
      }
      #pragma unroll
      for (int off = 1; off < 16; off <<= 1){
        ps += __shfl_xor(ps, off, 64);
        pd += __shfl_xor(pd, off, 64);
      }
      hs[h] = ps; hd[h] = pd;
    }
    if (cbase == 0 && row < N){
      *reinterpret_cast<float4*>(as1 + (size_t)row*4) = make_float4(hs[0],hs[1],hs[2],hs[3]);
      *reinterpret_cast<float4*>(ad1 + (size_t)row*4) = make_float4(hd[0],hd[1],hd[2],hd[3]);
    }
  }
}

// ---- layer-1 aggregation, FUSED exp: two nodes per wave (half-wave per node,
//      32 lanes x 8 ch). Phase 1: half computes its node's <=64 edge-exps
//      (2 slots/lane) into wave-local LDS + denominator in registers.
//      Phase 2: proven R18 gather+FMA stream, weights from LDS (fp32). ----
__global__ __launch_bounds__(256) void agg1_kernel(
                            const unsigned short* __restrict__ h1b,
                            const float* __restrict__ as1, const float* __restrict__ ad1,
                            const float* __restrict__ b1,
                            const int* __restrict__ cnt, const int* __restrict__ adj,
                            unsigned short* __restrict__ hact_b, int N){
  __shared__ float exlds[8][256];       // [wave*2+half][slot*4+head]
  int wid  = (blockIdx.x*blockDim.x + threadIdx.x) >> 6;
  int lane = threadIdx.x & 63;
  int hf   = lane >> 5;                 // which node of the pair
  int node = (wid << 1) + hf;
  if (node >= N) return;
  int sl = lane & 31;                   // channel slice: shorts sl*8 .. sl*8+7
  int hh = sl >> 3;                     // head of this lane's channels
  bool hb0 = (sl & 8) != 0, hb1 = (sl & 16) != 0;
  int cn = cnt[node]; if (cn > 64) cn = 64;
  unsigned beg = (unsigned)node << 6;
  const int* aj = adj + beg;
  unsigned co = (unsigned)sl * 8;
  int seg = (((threadIdx.x >> 6) & 3) << 1) + hf;
  float* exw = &exlds[seg][0];

  // ---- phase 1: per-edge exp (2 slots per lane), denominator in registers ----
  float4 dv4 = *reinterpret_cast<const float4*>(ad1 + (size_t)node*4);
  float4 sv4 = *reinterpret_cast<const float4*>(as1 + (size_t)node*4);
  float exs[4];
  exs[0] = __expf(lrelu(sv4.x + dv4.x));
  exs[1] = __expf(lrelu(sv4.y + dv4.y));
  exs[2] = __expf(lrelu(sv4.z + dv4.z));
  exs[3] = __expf(lrelu(sv4.w + dv4.w));
  float sp[4] = {0.f, 0.f, 0.f, 0.f};
  #pragma unroll
  for (int pass = 0; pass < 2; pass++){
    int s = sl + pass*32;
    bool val = s < cn;
    int src = val ? aj[s] : 0;
    float4 av = *reinterpret_cast<const float4*>(as1 + (size_t)src*4);
    float e0 = val ? __expf(lrelu(av.x + dv4.x)) : 0.f;
    float e1 = val ? __expf(lrelu(av.y + dv4.y)) : 0.f;
    float e2 = val ? __expf(lrelu(av.z + dv4.z)) : 0.f;
    float e3 = val ? __expf(lrelu(av.w + dv4.w)) : 0.f;
    *reinterpret_cast<float4*>(&exw[s*4]) = make_float4(e0, e1, e2, e3);
    sp[0] += e0; sp[1] += e1; sp[2] += e2; sp[3] += e3;
  }
  #pragma unroll
  for (int off = 1; off < 32; off <<= 1){
    #pragma unroll
    for (int k = 0; k < 4; k++) sp[k] += __shfl_xor(sp[k], off, 64);
  }
  #pragma unroll
  for (int k = 0; k < 4; k++) sp[k] += exs[k];
  float dh  = selh(sp[0], sp[1], sp[2], sp[3], hb0, hb1);
  float ehs = selh(exs[0], exs[1], exs[2], exs[3], hb0, hb1);

  // ---- phase 2: gather+FMA stream (R18 structure, weights from LDS) ----
  float acc[8];
  #pragma unroll
  for (int q = 0; q < 8; q++) acc[q] = 0.f;

  int j = 0;
  for (; j + 4 <= cn; j += 4){
    int s0 = aj[j], s1 = aj[j+1], s2 = aj[j+2], s3 = aj[j+3];
    float w0 = exw[(unsigned)(j+0)*4 + hh];
    float w1 = exw[(unsigned)(j+1)*4 + hh];
    float w2 = exw[(unsigned)(j+2)*4 + hh];
    float w3 = exw[(unsigned)(j+3)*4 + hh];
    uint4 h0 = *reinterpret_cast<const uint4*>(h1b + (((unsigned)s0 << 8) + co));
    uint4 h1 = *reinterpret_cast<const uint4*>(h1b + (((unsigned)s1 << 8) + co));
    uint4 h2 = *reinterpret_cast<const uint4*>(h1b + (((unsigned)s2 << 8) + co));
    uint4 h3 = *reinterpret_cast<const uint4*>(h1b + (((unsigned)s3 << 8) + co));
    FMA8(w0, h0); FMA8(w1, h1); FMA8(w2, h2); FMA8(w3, h3);
  }
  for (; j < cn; j++){
    int s0 = aj[j];
    float w0 = exw[(unsigned)j*4 + hh];
    uint4 h0 = *reinterpret_cast<const uint4*>(h1b + (((unsigned)s0 << 8) + co));
    FMA8(w0, h0);
  }

  // epilogue — fully per-half (this half owns all 256 channels of its node)
  uint4 hv = *reinterpret_cast<const uint4*>(h1b + (((unsigned)node << 8) + co));
  FMA8(ehs, hv);

  float rinv = 1.0f / (dh + 1e-16f);
  float4 bA = *reinterpret_cast<const float4*>(b1 + co);
  float4 bB = *reinterpret_cast<const float4*>(b1 + co + 4);
  float o[8];
  o[0] = acc[0]*rinv + bA.x; o[1] = acc[1]*rinv + bA.y;
  o[2] = acc[2]*rinv + bA.z; o[3] = acc[3]*rinv + bA.w;
  o[4] = acc[4]*rinv + bB.x; o[5] = acc[5]*rinv + bB.y;
  o[6] = acc[6]*rinv + bB.z; o[7] = acc[7]*rinv + bB.w;
  #pragma unroll
  for (int q = 0; q < 8; q++) o[q] = o[q] > 0.f ? o[q] : (__expf(o[q]) - 1.f);
  uint4 ob;
  ob.x = (unsigned)f2bf(o[0]) | ((unsigned)f2bf(o[1]) << 16);
  ob.y = (unsigned)f2bf(o[2]) | ((unsigned)f2bf(o[3]) << 16);
  ob.z = (unsigned)f2bf(o[4]) | ((unsigned)f2bf(o[5]) << 16);
  ob.w = (unsigned)f2bf(o[6]) | ((unsigned)f2bf(o[7]) << 16);
  *reinterpret_cast<uint4*>(hact_b + (((unsigned)node << 8) + co)) = ob;
}

// ---- GEMM2 via MFMA: h2 = hact_b @ W2  [N,256]x[256,16], fused alpha2 ----
__device__ __forceinline__ int wt2_addr(int col, int k){  // shorts, K=256
  int g = (k >> 3) ^ (col & 7);
  return col*256 + g*8 + (k & 7);
}

__global__ __launch_bounds__(256) void gemm2_mfma(const unsigned short* __restrict__ hact_b,
                             const float* __restrict__ W2,
                             const float* __restrict__ asrc2, const float* __restrict__ adst2,
                             float* __restrict__ h2, float* __restrict__ as2,
                             float* __restrict__ ad2, int N){
  __shared__ unsigned short wt[16*256];    // 8192 B
  int t = threadIdx.x;
  int lane = t & 63, w = t >> 6;
  int row0 = blockIdx.x * 64 + w * 16;

  // stage W2^T bf16: thread t owns k=t (row of W2), writes 16 cols
  {
    float4 r0 = *reinterpret_cast<const float4*>(W2 + (size_t)t*16);
    float4 r1 = *reinterpret_cast<const float4*>(W2 + (size_t)t*16 + 4);
    float4 r2 = *reinterpret_cast<const float4*>(W2 + (size_t)t*16 + 8);
    float4 r3 = *reinterpret_cast<const float4*>(W2 + (size_t)t*16 + 12);
    float wr[16] = {r0.x,r0.y,r0.z,r0.w, r1.x,r1.y,r1.z,r1.w,
                    r2.x,r2.y,r2.z,r2.w, r3.x,r3.y,r3.z,r3.w};
    #pragma unroll
    for (int cc = 0; cc < 16; cc++) wt[wt2_addr(cc, t)] = f2bf(wr[cc]);
  }

  // A-frag source row
  int arow = row0 + (lane & 15);
  if (arow >= N) arow = N - 1;
  const unsigned short* hr = hact_b + (size_t)arow*256 + (lane >> 4)*8;
  __syncthreads();

  f32x4 acc = (f32x4){0.f,0.f,0.f,0.f};
  #pragma unroll
  for (int kk = 0; kk < 8; kk++){
    bf16x8 a = *reinterpret_cast<const bf16x8*>(hr + kk*32);
    bf16x8 b = *reinterpret_cast<const bf16x8*>(
        &wt[wt2_addr(lane & 15, kk*32 + (lane >> 4)*8)]);
    acc = __builtin_amdgcn_mfma_f32_16x16x32_bf16(a, b, acc, 0, 0, 0);
  }

  // store h2 + fused alpha2 (cols = lane&15, rows = row0 + (lane>>4)*4 + r)
  int rbase = row0 + (lane >> 4)*4;
  int cbase = lane & 15;
  float avc = asrc2[cbase], dvc = adst2[cbase];
  #pragma unroll
  for (int r = 0; r < 4; r++){
    int row = rbase + r;
    if (row < N) h2[(size_t)row*16 + cbase] = acc[r];
    float ps = acc[r]*avc, pd = acc[r]*dvc;
    #pragma unroll
    for (int off = 1; off < 16; off <<= 1){
      ps += __shfl_xor(ps, off, 64);
      pd += __shfl_xor(pd, off, 64);
    }
    if (cbase == 0 && row < N){ as2[row] = ps; ad2[row] = pd; }
  }
}

// ---- layer-2 aggregation: single-chunk (cn<=64), shfl-decoupled. ----
__global__ void agg2_kernel(const float* __restrict__ h2, const float* __restrict__ as2,
                            const float* __restrict__ ad2, const float* __restrict__ b2,
                            const int* __restrict__ cnt, const int* __restrict__ adj,
                            float* __restrict__ out, int N){
  int node = (blockIdx.x*blockDim.x + threadIdx.x) >> 6;
  int lane = threadIdx.x & 63;
  if (node >= N) return;
  int cn = cnt[node]; if (cn > 64) cn = 64;
  int beg = node << 6;
  int g = lane >> 4, c = lane & 15;

  bool val = lane < cn;
  int srcl = val ? adj[beg + lane] : 0;   // invalid slots -> node 0 (safe address)
  float adn = ad2[node];

  // prefetch this group's h2 rows via shfl of srcl — independent of the exp chain
  float v[16];
  #pragma unroll
  for (int q = 0; q < 16; q++){
    v[q] = 0.f;
    if (4*q < cn){                        // uniform branch (cn wave-uniform)
      int sj = __shfl(srcl, 4*q + g, 64); // 0 for invalid slots
      v[q] = h2[((unsigned)sj*16u + (unsigned)c)];
    }
  }

  // exp chain: random 4B as2 gather, overlapped with the row loads above
  float e = val ? lrelu(as2[srcl] + adn) : -3e38f;
  float ex = __expf(e);                   // invalid -> 0
  float sp = ex;
  #pragma unroll
  for (int off = 32; off; off >>= 1) sp += __shfl_xor(sp, off, 64);
  float eself = __expf(lrelu(as2[node] + adn));
  sp += eself;

  float acc = 0.f;
  #pragma unroll
  for (int q = 0; q < 16; q++){
    if (4*q < cn){
      float wj = __shfl(ex, 4*q + g, 64); // 0 for invalid slots -> FMA no-op
      acc = fmaf(wj, v[q], acc);
    }
  }
  // combine group partials: lanes {c, c+16, c+32, c+48} hold same channel
  acc += __shfl_xor(acc, 16, 64);
  acc += __shfl_xor(acc, 32, 64);

  if (g == 0){   // lanes 0..15 finalize
    acc = fmaf(eself, h2[(size_t)node*16 + c], acc);
    float vv = acc / (sp + 1e-16f) + b2[c];
    float mx = vv;
    #pragma unroll
    for (int off = 1; off < 16; off <<= 1) mx = fmaxf(mx, __shfl_xor(mx, off, 64));
    float se = __expf(vv - mx);
    #pragma unroll
    for (int off = 1; off < 16; off <<= 1) se += __shfl_xor(se, off, 64);
    out[(size_t)node*16 + c] = vv - mx - logf(se);
  }
}

extern "C" void kernel_launch(void* const* d_in, const int* in_sizes, int n_in,
                              void* d_out, int out_size, void* d_ws, size_t ws_size,
                              hipStream_t stream){
  const float* x    = (const float*)d_in[0];
  const int*   ei   = (const int*)d_in[1];
  const float* W1   = (const float*)d_in[2];
  const float* as1w = (const float*)d_in[3];
  const float* ad1w = (const float*)d_in[4];
  const float* b1   = (const float*)d_in[5];
  const float* W2   = (const float*)d_in[6];
  const float* as2w = (const float*)d_in[7];
  const float* ad2w = (const float*)d_in[8];
  const float* b2   = (const float*)d_in[9];
  float* out = (float*)d_out;

  int N = in_sizes[0] / 128;   // 50000
  int E = in_sizes[1] / 2;     // 800000

  char* p = (char*)d_ws;
  size_t off = 0;
  auto alloc = [&](size_t b){ size_t c = off; off = (off + b + 255) & ~(size_t)255; return c; };
  unsigned short* h1b   = (unsigned short*)(p + alloc((size_t)N*256*2)); // 25.6 MB bf16
  unsigned short* hact_b= (unsigned short*)(p + alloc((size_t)N*256*2)); // 25.6 MB bf16
  float* h2     = (float*)(p + alloc((size_t)N*16*4));    // 3.2 MB
  float* as1    = (float*)(p + alloc((size_t)N*4*4));
  float* ad1    = (float*)(p + alloc((size_t)N*4*4));
  float* as2    = (float*)(p + alloc((size_t)N*4));
  float* ad2    = (float*)(p + alloc((size_t)N*4));
  int*   cnt    = (int*)(p + alloc((size_t)N*4));
  int*   adj    = (int*)(p + alloc((size_t)N*64*4));      // 12.8 MB bucket CSR

  hipMemsetAsync(cnt, 0, (size_t)N*4, stream);
  fill_kernel<<<2048, 256, 0, stream>>>(ei, cnt, adj, E);

  gemm1_mfma<<<(N + 63)/64, 256, 0, stream>>>(x, W1, as1w, ad1w, h1b, as1, ad1, N);
  agg1_kernel<<<(((N+1)/2)*64 + 255)/256, 256, 0, stream>>>(h1b, as1, ad1, b1, cnt, adj, hact_b, N);
  gemm2_mfma<<<(N + 63)/64, 256, 0, stream>>>(hact_b, W2, as2w, ad2w, h2, as2, ad2, N);
  agg2_kernel<<<(N*64 + 255)/256, 256, 0, stream>>>(h2, as2, ad2, b2, cnt, adj, out, N);
}